// Round 1
// baseline (272.650 us; speedup 1.0000x reference)
//
#include <hip/hip_runtime.h>

// GMLoss: bidirectional chamfer min + Geman-McClure penalty (MU=1).
// srcs, tgts: [B=8, D=3, N=4096] fp32. Output: scalar fp32.
//
// R19: SINGLE-PASS BIDIRECTIONAL chamfer. Previous best (R14, 72.6us) computed
// every pairwise distance TWICE (dir=0 srcs-vs-tgts, dir=1 tgts-vs-srcs).
// This version computes the distance matrix ONCE per batch and extracts BOTH
// mins: row-min (per-src, registers as before) and col-min (per-tgt: per-lane
// min over 4 regs x 4 row-tiles -> 2 shfl_xor across quads -> one 16-float
// partial store per col-tile). Halves MFMA tiles (1.05M -> 0.52M), halves
// B loads, halves chamfer blocks (1024 -> 512 = ONE resident round at 2/CU).
// Col partials [b][stripe][4096] (8MB, plain stores, written-once, no RMW)
// are stripe-min-reduced by a small 128-block kernel; b = blk&7 pins each
// batch to one XCD so both the B-pack reads and the colpart round-trip stay
// in that XCD's 4MB L2.
//
// Carried-over, counter-evidenced constraints:
//  - NO device-scope fences or bulk atomics in hot kernels (R7: 2M atomicMin
//    -> 478MB RMW traffic, 263us; R9: per-block __threadfence -> 70us floor).
//  - __launch_bounds__(256,2) on chamfer: cap-128 squeezes spill scratch.
//  - fp32 -> K=13 hi/lo bf16 packing, 16x16x32 MFMA with K-replication
//    (quads 2,3 re-read bytes 0..31 -> D=2P, halve after min).
//  - depth-4 register prefetch ring over B tiles.
// Accuracy: K=13 pack drops only lo.lo (~1e-5 << 1.26e-3 threshold).
//   A k: [-2sh(3), -2sl(3), -2sh(3), s2h, s2l, 1, 1, 0,0,0]
//   B k: [ th(3),   th(3),   tl(3),  1, 1, t2h, t2l, 0,0,0]
// 16x16x32 layouts (m89/m91): A[m=lane&15][k=(lane>>4)*8+j], B same
// (n=lane&15); D: col=lane&15, row=(lane>>4)*4+reg.
// Budget: ~40.5us harness d_ws re-poison (268MB fill, timed) + kernels.

#define NPTS 4096
#define NB   8

typedef __attribute__((ext_vector_type(8))) short bf16x8;
typedef __attribute__((ext_vector_type(4))) float floatx4;

// ws layout: Apack[srcs] (1MB), Bpack[tgts] (1MB), colpart (8MB), bsum[640]
#define OFF_APACK 0u
#define OFF_BPACK (1u << 20)
#define OFF_CPART (2u << 20)
#define OFF_BSUM  (10u << 20)

union V16 { int4 i; bf16x8 h; };

__device__ __forceinline__ unsigned short f2bf(float f) {
    unsigned u = __float_as_uint(f);
    u += 0x7FFFu + ((u >> 16) & 1u);       // RNE
    return (unsigned short)(u >> 16);
}
__device__ __forceinline__ float bf2f(unsigned short h) {
    return __uint_as_float(((unsigned)h) << 16);
}
__device__ __forceinline__ int pk(unsigned short lo, unsigned short hi) {
    return (int)((unsigned)lo | ((unsigned)hi << 16));
}

// ---------------- Kernel 1: pack A-style(srcs) + B-style(tgts) -------------
__device__ __forceinline__ void pack_A(const float* __restrict__ cloud,
                                       int b, int j, int gid,
                                       char* __restrict__ apack) {
    const unsigned short ONE = 0x3F80;
    const float* p = cloud + b * 3 * NPTS;
    const float x = p[j], y = p[NPTS + j], z = p[2 * NPTS + j];
    const unsigned short hx = f2bf(x), hy = f2bf(y), hz = f2bf(z);
    const unsigned short a0 = f2bf(-2.0f * bf2f(hx));
    const unsigned short a1 = f2bf(-2.0f * bf2f(hy));
    const unsigned short a2 = f2bf(-2.0f * bf2f(hz));
    const unsigned short m0 = f2bf(-2.0f * (x - bf2f(hx)));
    const unsigned short m1 = f2bf(-2.0f * (y - bf2f(hy)));
    const unsigned short m2 = f2bf(-2.0f * (z - bf2f(hz)));
    const float n2 = fmaf(z, z, fmaf(y, y, x * x));
    const unsigned short n2h = f2bf(n2);
    const unsigned short n2l = f2bf(n2 - bf2f(n2h));
    int4* Ap = (int4*)(apack + (size_t)gid * 32);
    Ap[0] = make_int4(pk(a0, a1), pk(a2, m0), pk(m1, m2), pk(a0, a1));
    Ap[1] = make_int4(pk(a2, n2h), pk(n2l, ONE), pk(ONE, 0), 0);
}

__device__ __forceinline__ void pack_B(const float* __restrict__ cloud,
                                       int b, int j, int gid,
                                       char* __restrict__ bpack) {
    const unsigned short ONE = 0x3F80;
    const float* p = cloud + b * 3 * NPTS;
    const float x = p[j], y = p[NPTS + j], z = p[2 * NPTS + j];
    const unsigned short hx = f2bf(x), hy = f2bf(y), hz = f2bf(z);
    const unsigned short lx = f2bf(x - bf2f(hx));
    const unsigned short ly = f2bf(y - bf2f(hy));
    const unsigned short lz = f2bf(z - bf2f(hz));
    const float n2 = fmaf(z, z, fmaf(y, y, x * x));
    const unsigned short n2h = f2bf(n2);
    const unsigned short n2l = f2bf(n2 - bf2f(n2h));
    int4* Bp = (int4*)(bpack + (size_t)gid * 32);
    Bp[0] = make_int4(pk(hx, hy), pk(hz, hx), pk(hy, hz), pk(lx, ly));
    Bp[1] = make_int4(pk(lz, ONE), pk(ONE, n2h), pk(n2l, 0), 0);
}

__global__ __launch_bounds__(256)
void transform_kernel(const float* __restrict__ srcs,
                      const float* __restrict__ tgts,
                      char* __restrict__ ws) {
    const int gid = blockIdx.x * 256 + threadIdx.x;   // 0..32767 = b*4096+j
    const int b = gid >> 12, j = gid & 4095;
    pack_A(srcs, b, j, gid, ws + OFF_APACK);
    pack_B(tgts, b, j, gid, ws + OFF_BPACK);
}

// ------- Kernel 2: single-pass bidirectional MFMA chamfer (64 rows) -------
__global__ __launch_bounds__(256, 2)
void chamfer_kernel(char* __restrict__ ws) {
    const int blk    = blockIdx.x;        // 0..511
    const int b      = blk & 7;           // XCD-pinned batch
    const int stripe = blk >> 3;          // 0..63, 64 src rows each
    const int tid    = threadIdx.x;
    const int wave   = tid >> 6;          // 0..3
    const int lane   = tid & 63;
    const int l15    = lane & 15;
    const int quad   = lane >> 4;         // k-half = (quad&1)*16 bytes

    const char* Ap = ws + OFF_APACK;
    const char* Bp = ws + OFF_BPACK;
    float* cpart = (float*)(ws + OFF_CPART) + (size_t)(b * 64 + stripe) * NPTS;

    // 4 row-tiles of 16 rows; quads 2,3 replicate quads 0,1 -> D = 2P.
    V16 av[4];
#pragma unroll
    for (int rt = 0; rt < 4; rt++)
        av[rt].i = *(const int4*)(Ap +
            (size_t)(b * NPTS + stripe * 64 + rt * 16 + l15) * 32 + (quad & 1) * 16);

    floatx4 rmin[4];
#pragma unroll
    for (int rt = 0; rt < 4; rt++)
        rmin[rt] = (floatx4){3.0e38f, 3.0e38f, 3.0e38f, 3.0e38f};
    const floatx4 zero = {0.0f, 0.0f, 0.0f, 0.0f};

    const int ct0 = wave * 64;            // 64 col-tiles (of 16 pts) per wave
    const char* bbase = Bp + (size_t)(b * NPTS + ct0 * 16 + l15) * 32 + (quad & 1) * 16;
    float* cbase = cpart + ct0 * 16 + l15;

    // depth-4 register prefetch ring over 64 tiles, 512 B apart; wrap &63
    V16 t0, t1, t2, t3;
    t0.i = *(const int4*)(bbase);
    t1.i = *(const int4*)(bbase + 512);
    t2.i = *(const int4*)(bbase + 1024);
    t3.i = *(const int4*)(bbase + 1536);

#pragma unroll
    for (int i = 0; i < 64; i += 4) {
        V16 n0, n1, n2, n3;
        n0.i = *(const int4*)(bbase + (size_t)((i + 4) & 63) * 512);
        n1.i = *(const int4*)(bbase + (size_t)((i + 5) & 63) * 512);
        n2.i = *(const int4*)(bbase + (size_t)((i + 6) & 63) * 512);
        n3.i = *(const int4*)(bbase + (size_t)((i + 7) & 63) * 512);
#pragma unroll
        for (int u = 0; u < 4; u++) {
            const bf16x8 bf = (u == 0 ? t0.h : u == 1 ? t1.h : u == 2 ? t2.h : t3.h);
            float colacc = 3.0e38f;       // min over this lane's 16 rows
#pragma unroll
            for (int rt = 0; rt < 4; rt++) {
                const floatx4 d =
                    __builtin_amdgcn_mfma_f32_16x16x32_bf16(av[rt].h, bf, zero, 0, 0, 0);
#pragma unroll
                for (int r = 0; r < 4; r++)
                    rmin[rt][r] = fminf(rmin[rt][r], d[r]);
                colacc = fminf(colacc,
                               fminf(fminf(d[0], d[1]), fminf(d[2], d[3])));
            }
            // combine quads -> min over all 64 block rows, col = tile*16+l15
            colacc = fminf(colacc, __shfl_xor(colacc, 16, 64));
            colacc = fminf(colacc, __shfl_xor(colacc, 32, 64));
            if (quad == 0)
                cbase[(i + u) * 16] = colacc;   // plain store, written-once
        }
        t0 = n0; t1 = n1; t2 = n2; t3 = n3;
    }

    // ---- row side: butterfly min over the 16 col-lanes ----
#pragma unroll
    for (int off = 1; off < 16; off <<= 1) {
#pragma unroll
        for (int rt = 0; rt < 4; rt++)
#pragma unroll
            for (int r = 0; r < 4; r++)
                rmin[rt][r] = fminf(rmin[rt][r], __shfl_xor(rmin[rt][r], off, 64));
    }
    // quad leader holds rows rt*16 + quad*4 + r
    __shared__ float sRow[4][64];
    if (l15 == 0) {
#pragma unroll
        for (int rt = 0; rt < 4; rt++)
#pragma unroll
            for (int r = 0; r < 4; r++)
                sRow[wave][rt * 16 + quad * 4 + r] = rmin[rt][r];
    }
    __syncthreads();
    if (tid < 64) {
        float m = fminf(fminf(sRow[0][tid], sRow[1][tid]),
                        fminf(sRow[2][tid], sRow[3][tid]));
        m = fmaxf(m * 0.5f, 0.0f);        // undo K-replication doubling
        float g = m / (m + 1.0f);         // GM, MU=1
#pragma unroll
        for (int off = 1; off < 64; off <<= 1)
            g += __shfl_xor(g, off, 64);
        if (tid == 0)
            ((float*)(ws + OFF_BSUM))[blk] = g;   // plain store
    }
}

// ---- Kernel 3: stripe-min reduce of col partials + GM partial sums -------
__global__ __launch_bounds__(256)
void colreduce_kernel(char* __restrict__ ws) {
    const int blk = blockIdx.x;           // 0..127
    const int b   = blk & 7;              // match chamfer's XCD pinning
    const int cc  = blk >> 3;             // 0..15, 256-col chunk
    const int tid = threadIdx.x;
    const float* cp = (const float*)(ws + OFF_CPART) +
                      (size_t)b * 64 * NPTS + cc * 256 + tid;
    float m0 = 3.0e38f, m1 = 3.0e38f, m2 = 3.0e38f, m3 = 3.0e38f;
#pragma unroll 4
    for (int s = 0; s < 64; s += 4) {     // 4 chains for load ILP
        m0 = fminf(m0, cp[(size_t)(s + 0) * NPTS]);
        m1 = fminf(m1, cp[(size_t)(s + 1) * NPTS]);
        m2 = fminf(m2, cp[(size_t)(s + 2) * NPTS]);
        m3 = fminf(m3, cp[(size_t)(s + 3) * NPTS]);
    }
    float m = fminf(fminf(m0, m1), fminf(m2, m3));
    m = fmaxf(m * 0.5f, 0.0f);            // undo K-replication doubling
    float g = m / (m + 1.0f);             // GM, MU=1
#pragma unroll
    for (int off = 1; off < 64; off <<= 1)
        g += __shfl_xor(g, off, 64);
    __shared__ float sp[4];
    if ((tid & 63) == 0) sp[tid >> 6] = g;
    __syncthreads();
    if (tid == 0)
        ((float*)(ws + OFF_BSUM))[512 + blk] = sp[0] + sp[1] + sp[2] + sp[3];
}

// ---------------- Kernel 4: single-block finish ----------------
__global__ __launch_bounds__(256)
void final_kernel(const char* __restrict__ ws, float* __restrict__ out) {
    const float* bsum = (const float*)(ws + OFF_BSUM);
    const int tid = threadIdx.x;
    float g = bsum[tid] + bsum[tid + 256];          // row-side 512 partials
    if (tid < 128) g += bsum[512 + tid];            // col-side 128 partials
#pragma unroll
    for (int off = 1; off < 64; off <<= 1)
        g += __shfl_xor(g, off, 64);
    __shared__ float sp[4];
    if ((tid & 63) == 0) sp[tid >> 6] = g;
    __syncthreads();
    if (tid == 0)
        out[0] = (sp[0] + sp[1] + sp[2] + sp[3]) * (1.0f / (NB * NPTS));
}

extern "C" void kernel_launch(void* const* d_in, const int* in_sizes, int n_in,
                              void* d_out, int out_size, void* d_ws, size_t ws_size,
                              hipStream_t stream) {
    const float* srcs = (const float*)d_in[0];
    const float* tgts = (const float*)d_in[1];
    float* out = (float*)d_out;
    char* ws = (char*)d_ws;

    transform_kernel<<<dim3(128), dim3(256), 0, stream>>>(srcs, tgts, ws);
    chamfer_kernel<<<dim3(512), dim3(256), 0, stream>>>(ws);
    colreduce_kernel<<<dim3(128), dim3(256), 0, stream>>>(ws);
    final_kernel<<<dim3(1), dim3(256), 0, stream>>>(ws, out);
}

// Round 2
// 270.682 us; speedup vs baseline: 1.0073x; 1.0073x over previous
//
#include <hip/hip_runtime.h>

// GMLoss: bidirectional chamfer min + Geman-McClure penalty (MU=1).
// srcs, tgts: [B=8, D=3, N=4096] fp32. Output: scalar fp32.
//
// R20: single-pass bidirectional chamfer (R19 algorithm) with the R14 hot-loop
// shape restored. R19 regressed 72.6 -> 272us because it stored col-min
// partials to GLOBAL (via ws) inside the MFMA loop: cpart and Bpack derive
// from the same ws pointer, so the compiler couldn't prove no-alias, the
// depth-4 prefetch batching collapsed, and values spilled to scratch
// (FETCH 203MB + WRITE 412MB of pure scratch/alias traffic = the whole
// 210us). Fix: col-mins buffered in LDS (quad-0 lanes, 4KB/wave) during the
// loop; ONE coalesced float4 burst to cpart after the loop. Hot loop is now
// ring-loads + MFMA + fminf + 2 shfl per 16 MFMAs -- no global stores.
//
// Invariants (counter-evidenced, 20 rounds):
//  - NO global stores through ws inside the MFMA loop (R19: alias -> spill).
//  - NO device-scope fences or bulk atomics in hot kernels (R7/R9).
//  - __launch_bounds__(256,2) on chamfer.
//  - fp32 -> K=13 hi/lo bf16 packing, 16x16x32 MFMA with K-replication
//    (quads 2,3 re-read bytes 0..31 -> D=2P, halve after min).
//  - depth-4 register prefetch ring over B tiles.
// Single-pass: distance matrix computed ONCE per batch; row-min (per-src) in
// registers, col-min (per-tgt) via per-lane min + 2 shfl_xor -> LDS -> cpart
// [b][stripe][4096] (8MB, written-once), stripe-min-reduced by colreduce.
// b = blk&7 pins each batch's Bpack + cpart round-trip to one XCD's L2.
// Accuracy: K=13 pack drops only lo.lo (~1e-5 << 1.26e-3 threshold).
//   A k: [-2sh(3), -2sl(3), -2sh(3), s2h, s2l, 1, 1, 0,0,0]
//   B k: [ th(3),   th(3),   tl(3),  1, 1, t2h, t2l, 0,0,0]
// 16x16x32 layouts (m89/m91): A[m=lane&15][k=(lane>>4)*8+j], B same
// (n=lane&15); D: col=lane&15, row=(lane>>4)*4+reg.
// Budget: ~40.5us harness d_ws re-poison (268MB fill, timed) + kernels.

#define NPTS 4096
#define NB   8

typedef __attribute__((ext_vector_type(8))) short bf16x8;
typedef __attribute__((ext_vector_type(4))) float floatx4;

// ws layout: Apack[srcs] (1MB), Bpack[tgts] (1MB), colpart (8MB), bsum[640]
#define OFF_APACK 0u
#define OFF_BPACK (1u << 20)
#define OFF_CPART (2u << 20)
#define OFF_BSUM  (10u << 20)

union V16 { int4 i; bf16x8 h; };

__device__ __forceinline__ unsigned short f2bf(float f) {
    unsigned u = __float_as_uint(f);
    u += 0x7FFFu + ((u >> 16) & 1u);       // RNE
    return (unsigned short)(u >> 16);
}
__device__ __forceinline__ float bf2f(unsigned short h) {
    return __uint_as_float(((unsigned)h) << 16);
}
__device__ __forceinline__ int pk(unsigned short lo, unsigned short hi) {
    return (int)((unsigned)lo | ((unsigned)hi << 16));
}

// ---------------- Kernel 1: pack A-style(srcs) + B-style(tgts) -------------
__device__ __forceinline__ void pack_A(const float* __restrict__ cloud,
                                       int b, int j, int gid,
                                       char* __restrict__ apack) {
    const unsigned short ONE = 0x3F80;
    const float* p = cloud + b * 3 * NPTS;
    const float x = p[j], y = p[NPTS + j], z = p[2 * NPTS + j];
    const unsigned short hx = f2bf(x), hy = f2bf(y), hz = f2bf(z);
    const unsigned short a0 = f2bf(-2.0f * bf2f(hx));
    const unsigned short a1 = f2bf(-2.0f * bf2f(hy));
    const unsigned short a2 = f2bf(-2.0f * bf2f(hz));
    const unsigned short m0 = f2bf(-2.0f * (x - bf2f(hx)));
    const unsigned short m1 = f2bf(-2.0f * (y - bf2f(hy)));
    const unsigned short m2 = f2bf(-2.0f * (z - bf2f(hz)));
    const float n2 = fmaf(z, z, fmaf(y, y, x * x));
    const unsigned short n2h = f2bf(n2);
    const unsigned short n2l = f2bf(n2 - bf2f(n2h));
    int4* Ap = (int4*)(apack + (size_t)gid * 32);
    Ap[0] = make_int4(pk(a0, a1), pk(a2, m0), pk(m1, m2), pk(a0, a1));
    Ap[1] = make_int4(pk(a2, n2h), pk(n2l, ONE), pk(ONE, 0), 0);
}

__device__ __forceinline__ void pack_B(const float* __restrict__ cloud,
                                       int b, int j, int gid,
                                       char* __restrict__ bpack) {
    const unsigned short ONE = 0x3F80;
    const float* p = cloud + b * 3 * NPTS;
    const float x = p[j], y = p[NPTS + j], z = p[2 * NPTS + j];
    const unsigned short hx = f2bf(x), hy = f2bf(y), hz = f2bf(z);
    const unsigned short lx = f2bf(x - bf2f(hx));
    const unsigned short ly = f2bf(y - bf2f(hy));
    const unsigned short lz = f2bf(z - bf2f(hz));
    const float n2 = fmaf(z, z, fmaf(y, y, x * x));
    const unsigned short n2h = f2bf(n2);
    const unsigned short n2l = f2bf(n2 - bf2f(n2h));
    int4* Bp = (int4*)(bpack + (size_t)gid * 32);
    Bp[0] = make_int4(pk(hx, hy), pk(hz, hx), pk(hy, hz), pk(lx, ly));
    Bp[1] = make_int4(pk(lz, ONE), pk(ONE, n2h), pk(n2l, 0), 0);
}

__global__ __launch_bounds__(256)
void transform_kernel(const float* __restrict__ srcs,
                      const float* __restrict__ tgts,
                      char* __restrict__ ws) {
    const int gid = blockIdx.x * 256 + threadIdx.x;   // 0..32767 = b*4096+j
    const int b = gid >> 12, j = gid & 4095;
    pack_A(srcs, b, j, gid, ws + OFF_APACK);
    pack_B(tgts, b, j, gid, ws + OFF_BPACK);
}

// ------- Kernel 2: single-pass bidirectional MFMA chamfer (64 rows) -------
__global__ __launch_bounds__(256, 2)
void chamfer_kernel(char* __restrict__ ws) {
    const int blk    = blockIdx.x;        // 0..511
    const int b      = blk & 7;           // XCD-pinned batch
    const int stripe = blk >> 3;          // 0..63, 64 src rows each
    const int tid    = threadIdx.x;
    const int wave   = tid >> 6;          // 0..3
    const int lane   = tid & 63;
    const int l15    = lane & 15;
    const int quad   = lane >> 4;         // k-half = (quad&1)*16 bytes

    const char* Ap = ws + OFF_APACK;
    const char* Bp = ws + OFF_BPACK;

    __shared__ __align__(16) float sCol[4][1024];   // per-wave col-min buffer
    __shared__ float sRow[4][64];

    // 4 row-tiles of 16 rows; quads 2,3 replicate quads 0,1 -> D = 2P.
    V16 av[4];
#pragma unroll
    for (int rt = 0; rt < 4; rt++)
        av[rt].i = *(const int4*)(Ap +
            (size_t)(b * NPTS + stripe * 64 + rt * 16 + l15) * 32 + (quad & 1) * 16);

    floatx4 rmin[4];
#pragma unroll
    for (int rt = 0; rt < 4; rt++)
        rmin[rt] = (floatx4){3.0e38f, 3.0e38f, 3.0e38f, 3.0e38f};
    const floatx4 zero = {0.0f, 0.0f, 0.0f, 0.0f};

    const int ct0 = wave * 64;            // 64 col-tiles (of 16 pts) per wave
    const char* bbase = Bp + (size_t)(b * NPTS + ct0 * 16 + l15) * 32 + (quad & 1) * 16;

    // depth-4 register prefetch ring over 64 tiles, 512 B apart; wrap &63
    V16 t0, t1, t2, t3;
    t0.i = *(const int4*)(bbase);
    t1.i = *(const int4*)(bbase + 512);
    t2.i = *(const int4*)(bbase + 1024);
    t3.i = *(const int4*)(bbase + 1536);

#pragma unroll
    for (int i = 0; i < 64; i += 4) {
        V16 n0, n1, n2, n3;
        n0.i = *(const int4*)(bbase + (size_t)((i + 4) & 63) * 512);
        n1.i = *(const int4*)(bbase + (size_t)((i + 5) & 63) * 512);
        n2.i = *(const int4*)(bbase + (size_t)((i + 6) & 63) * 512);
        n3.i = *(const int4*)(bbase + (size_t)((i + 7) & 63) * 512);
#pragma unroll
        for (int u = 0; u < 4; u++) {
            const bf16x8 bf = (u == 0 ? t0.h : u == 1 ? t1.h : u == 2 ? t2.h : t3.h);
            float colacc = 3.0e38f;       // min over this quad's 16 rows
#pragma unroll
            for (int rt = 0; rt < 4; rt++) {
                const floatx4 d =
                    __builtin_amdgcn_mfma_f32_16x16x32_bf16(av[rt].h, bf, zero, 0, 0, 0);
#pragma unroll
                for (int r = 0; r < 4; r++)
                    rmin[rt][r] = fminf(rmin[rt][r], d[r]);
                colacc = fminf(colacc,
                               fminf(fminf(d[0], d[1]), fminf(d[2], d[3])));
            }
            // combine quads -> min over all 64 block rows; col = tile*16+l15
            colacc = fminf(colacc, __shfl_xor(colacc, 16, 64));
            colacc = fminf(colacc, __shfl_xor(colacc, 32, 64));
            if (quad == 0)
                sCol[wave][(i + u) * 16 + l15] = colacc;   // LDS, not global
        }
        t0 = n0; t1 = n1; t2 = n2; t3 = n3;
    }

    // ---- col side: one coalesced burst of this wave's 1024 partials ----
    {
        float4* cp4 = (float4*)((float*)(ws + OFF_CPART) +
                                (size_t)(b * 64 + stripe) * NPTS + ct0 * 16);
        const float4* s4 = (const float4*)sCol[wave];
#pragma unroll
        for (int k2 = 0; k2 < 4; k2++)
            cp4[k2 * 64 + lane] = s4[k2 * 64 + lane];
    }

    // ---- row side: butterfly min over the 16 col-lanes ----
#pragma unroll
    for (int off = 1; off < 16; off <<= 1) {
#pragma unroll
        for (int rt = 0; rt < 4; rt++)
#pragma unroll
            for (int r = 0; r < 4; r++)
                rmin[rt][r] = fminf(rmin[rt][r], __shfl_xor(rmin[rt][r], off, 64));
    }
    // quad leader holds rows rt*16 + quad*4 + r
    if (l15 == 0) {
#pragma unroll
        for (int rt = 0; rt < 4; rt++)
#pragma unroll
            for (int r = 0; r < 4; r++)
                sRow[wave][rt * 16 + quad * 4 + r] = rmin[rt][r];
    }
    __syncthreads();
    if (tid < 64) {
        float m = fminf(fminf(sRow[0][tid], sRow[1][tid]),
                        fminf(sRow[2][tid], sRow[3][tid]));
        m = fmaxf(m * 0.5f, 0.0f);        // undo K-replication doubling
        float g = m / (m + 1.0f);         // GM, MU=1
#pragma unroll
        for (int off = 1; off < 64; off <<= 1)
            g += __shfl_xor(g, off, 64);
        if (tid == 0)
            ((float*)(ws + OFF_BSUM))[blk] = g;   // plain store
    }
}

// ---- Kernel 3: stripe-min reduce of col partials + GM partial sums -------
__global__ __launch_bounds__(256)
void colreduce_kernel(char* __restrict__ ws) {
    const int blk = blockIdx.x;           // 0..127
    const int b   = blk & 7;              // match chamfer's XCD pinning
    const int cc  = blk >> 3;             // 0..15, 256-col chunk
    const int tid = threadIdx.x;
    const float* cp = (const float*)(ws + OFF_CPART) +
                      (size_t)b * 64 * NPTS + cc * 256 + tid;
    float m0 = 3.0e38f, m1 = 3.0e38f, m2 = 3.0e38f, m3 = 3.0e38f;
#pragma unroll 4
    for (int s = 0; s < 64; s += 4) {     // 4 chains for load ILP
        m0 = fminf(m0, cp[(size_t)(s + 0) * NPTS]);
        m1 = fminf(m1, cp[(size_t)(s + 1) * NPTS]);
        m2 = fminf(m2, cp[(size_t)(s + 2) * NPTS]);
        m3 = fminf(m3, cp[(size_t)(s + 3) * NPTS]);
    }
    float m = fminf(fminf(m0, m1), fminf(m2, m3));
    m = fmaxf(m * 0.5f, 0.0f);            // undo K-replication doubling
    float g = m / (m + 1.0f);             // GM, MU=1
#pragma unroll
    for (int off = 1; off < 64; off <<= 1)
        g += __shfl_xor(g, off, 64);
    __shared__ float sp[4];
    if ((tid & 63) == 0) sp[tid >> 6] = g;
    __syncthreads();
    if (tid == 0)
        ((float*)(ws + OFF_BSUM))[512 + blk] = sp[0] + sp[1] + sp[2] + sp[3];
}

// ---------------- Kernel 4: single-block finish ----------------
__global__ __launch_bounds__(256)
void final_kernel(const char* __restrict__ ws, float* __restrict__ out) {
    const float* bsum = (const float*)(ws + OFF_BSUM);
    const int tid = threadIdx.x;
    float g = bsum[tid] + bsum[tid + 256];          // row-side 512 partials
    if (tid < 128) g += bsum[512 + tid];            // col-side 128 partials
#pragma unroll
    for (int off = 1; off < 64; off <<= 1)
        g += __shfl_xor(g, off, 64);
    __shared__ float sp[4];
    if ((tid & 63) == 0) sp[tid >> 6] = g;
    __syncthreads();
    if (tid == 0)
        out[0] = (sp[0] + sp[1] + sp[2] + sp[3]) * (1.0f / (NB * NPTS));
}

extern "C" void kernel_launch(void* const* d_in, const int* in_sizes, int n_in,
                              void* d_out, int out_size, void* d_ws, size_t ws_size,
                              hipStream_t stream) {
    const float* srcs = (const float*)d_in[0];
    const float* tgts = (const float*)d_in[1];
    float* out = (float*)d_out;
    char* ws = (char*)d_ws;

    transform_kernel<<<dim3(128), dim3(256), 0, stream>>>(srcs, tgts, ws);
    chamfer_kernel<<<dim3(512), dim3(256), 0, stream>>>(ws);
    colreduce_kernel<<<dim3(128), dim3(256), 0, stream>>>(ws);
    final_kernel<<<dim3(1), dim3(256), 0, stream>>>(ws, out);
}

// Round 4
// 88.746 us; speedup vs baseline: 3.0722x; 3.0501x over previous
//
#include <hip/hip_runtime.h>

// GMLoss: bidirectional chamfer min + Geman-McClure penalty (MU=1).
// srcs, tgts: [B=8, D=3, N=4096] fp32. Output: scalar fp32.
//
// R22 = R21 resubmit (R3 bench was an infra failure: "container failed
// twice", no compile/test diagnostics -> hypothesis untested). One delta vs
// R21: dropped the per-u-step sched_barrier(0) intrinsics; #pragma unroll 1
// on the i-loop is the load-bearing fix and the only structural difference
// from R20's spilling kernel.
//
// History of the single-pass attempts:
//  - R19 (global col-store in loop) and R20 (LDS col-store in loop) BOTH
//    regressed to ~245us with IDENTICAL counters: FETCH 203MB, WRITE 412MB
//    (= 3.1KB/thread scratch spill), MfmaUtil 1.4%, latency-bound.
//    Store mechanism irrelevant -> spill comes from the scheduler hoisting
//    MFMAs across the fully-unrolled 16-iteration i-loop to hide latency:
//    the col-min path adds a serial consumer chain per d, the scheduler
//    responds by keeping dozens of floatx4 d values live -> VGPR overflow.
//  - Fix: #pragma unroll 1 on the i-loop -> one 16-MFMA ring batch per
//    trip, d values dead at the backedge, no cross-iteration hoisting.
//
// Invariants (counter-evidenced, 22 rounds):
//  - Bound the MFMA live-range window when d has multi-consumer chains
//    (R19/R20: 600MB scratch traffic otherwise).
//  - NO device-scope fences or bulk atomics in hot kernels (R7/R9).
//  - __launch_bounds__(256,2) on chamfer.
//  - fp32 -> K=13 hi/lo bf16 packing, 16x16x32 MFMA with K-replication
//    (quads 2,3 re-read bytes 0..31 -> D=2P, halve after min).
//  - depth-4 register prefetch ring over B tiles.
// Single-pass: distance matrix computed ONCE per batch; row-min (per-src) in
// registers, col-min (per-tgt) via per-lane min + 2 shfl_xor -> LDS -> cpart
// [b][stripe][4096] (8MB, written-once), stripe-min-reduced by colreduce.
// b = blk&7 pins each batch's Bpack + cpart round-trip to one XCD's L2.
// Accuracy: K=13 pack drops only lo.lo (~1e-5 << 1.26e-3 threshold); single-
// pass absmax was 0.0 on R19/R20.
//   A k: [-2sh(3), -2sl(3), -2sh(3), s2h, s2l, 1, 1, 0,0,0]
//   B k: [ th(3),   th(3),   tl(3),  1, 1, t2h, t2l, 0,0,0]
// 16x16x32 layouts (m89/m91): A[m=lane&15][k=(lane>>4)*8+j], B same
// (n=lane&15); D: col=lane&15, row=(lane>>4)*4+reg.
// Budget: ~40.5us harness d_ws re-poison (268MB fill, timed) + kernels.

#define NPTS 4096
#define NB   8

typedef __attribute__((ext_vector_type(8))) short bf16x8;
typedef __attribute__((ext_vector_type(4))) float floatx4;

// ws layout: Apack[srcs] (1MB), Bpack[tgts] (1MB), colpart (8MB), bsum[640]
#define OFF_APACK 0u
#define OFF_BPACK (1u << 20)
#define OFF_CPART (2u << 20)
#define OFF_BSUM  (10u << 20)

union V16 { int4 i; bf16x8 h; };

__device__ __forceinline__ unsigned short f2bf(float f) {
    unsigned u = __float_as_uint(f);
    u += 0x7FFFu + ((u >> 16) & 1u);       // RNE
    return (unsigned short)(u >> 16);
}
__device__ __forceinline__ float bf2f(unsigned short h) {
    return __uint_as_float(((unsigned)h) << 16);
}
__device__ __forceinline__ int pk(unsigned short lo, unsigned short hi) {
    return (int)((unsigned)lo | ((unsigned)hi << 16));
}

// ---------------- Kernel 1: pack A-style(srcs) + B-style(tgts) -------------
__device__ __forceinline__ void pack_A(const float* __restrict__ cloud,
                                       int b, int j, int gid,
                                       char* __restrict__ apack) {
    const unsigned short ONE = 0x3F80;
    const float* p = cloud + b * 3 * NPTS;
    const float x = p[j], y = p[NPTS + j], z = p[2 * NPTS + j];
    const unsigned short hx = f2bf(x), hy = f2bf(y), hz = f2bf(z);
    const unsigned short a0 = f2bf(-2.0f * bf2f(hx));
    const unsigned short a1 = f2bf(-2.0f * bf2f(hy));
    const unsigned short a2 = f2bf(-2.0f * bf2f(hz));
    const unsigned short m0 = f2bf(-2.0f * (x - bf2f(hx)));
    const unsigned short m1 = f2bf(-2.0f * (y - bf2f(hy)));
    const unsigned short m2 = f2bf(-2.0f * (z - bf2f(hz)));
    const float n2 = fmaf(z, z, fmaf(y, y, x * x));
    const unsigned short n2h = f2bf(n2);
    const unsigned short n2l = f2bf(n2 - bf2f(n2h));
    int4* Ap = (int4*)(apack + (size_t)gid * 32);
    Ap[0] = make_int4(pk(a0, a1), pk(a2, m0), pk(m1, m2), pk(a0, a1));
    Ap[1] = make_int4(pk(a2, n2h), pk(n2l, ONE), pk(ONE, 0), 0);
}

__device__ __forceinline__ void pack_B(const float* __restrict__ cloud,
                                       int b, int j, int gid,
                                       char* __restrict__ bpack) {
    const unsigned short ONE = 0x3F80;
    const float* p = cloud + b * 3 * NPTS;
    const float x = p[j], y = p[NPTS + j], z = p[2 * NPTS + j];
    const unsigned short hx = f2bf(x), hy = f2bf(y), hz = f2bf(z);
    const unsigned short lx = f2bf(x - bf2f(hx));
    const unsigned short ly = f2bf(y - bf2f(hy));
    const unsigned short lz = f2bf(z - bf2f(hz));
    const float n2 = fmaf(z, z, fmaf(y, y, x * x));
    const unsigned short n2h = f2bf(n2);
    const unsigned short n2l = f2bf(n2 - bf2f(n2h));
    int4* Bp = (int4*)(bpack + (size_t)gid * 32);
    Bp[0] = make_int4(pk(hx, hy), pk(hz, hx), pk(hy, hz), pk(lx, ly));
    Bp[1] = make_int4(pk(lz, ONE), pk(ONE, n2h), pk(n2l, 0), 0);
}

__global__ __launch_bounds__(256)
void transform_kernel(const float* __restrict__ srcs,
                      const float* __restrict__ tgts,
                      char* __restrict__ ws) {
    const int gid = blockIdx.x * 256 + threadIdx.x;   // 0..32767 = b*4096+j
    const int b = gid >> 12, j = gid & 4095;
    pack_A(srcs, b, j, gid, ws + OFF_APACK);
    pack_B(tgts, b, j, gid, ws + OFF_BPACK);
}

// ------- Kernel 2: single-pass bidirectional MFMA chamfer (64 rows) -------
__global__ __launch_bounds__(256, 2)
void chamfer_kernel(char* __restrict__ ws) {
    const int blk    = blockIdx.x;        // 0..511
    const int b      = blk & 7;           // XCD-pinned batch
    const int stripe = blk >> 3;          // 0..63, 64 src rows each
    const int tid    = threadIdx.x;
    const int wave   = tid >> 6;          // 0..3
    const int lane   = tid & 63;
    const int l15    = lane & 15;
    const int quad   = lane >> 4;         // k-half = (quad&1)*16 bytes

    const char* Ap = ws + OFF_APACK;
    const char* Bp = ws + OFF_BPACK;

    __shared__ __align__(16) float sCol[4][1024];   // per-wave col-min buffer
    __shared__ float sRow[4][64];

    // 4 row-tiles of 16 rows; quads 2,3 replicate quads 0,1 -> D = 2P.
    V16 av[4];
#pragma unroll
    for (int rt = 0; rt < 4; rt++)
        av[rt].i = *(const int4*)(Ap +
            (size_t)(b * NPTS + stripe * 64 + rt * 16 + l15) * 32 + (quad & 1) * 16);

    floatx4 rmin[4];
#pragma unroll
    for (int rt = 0; rt < 4; rt++)
        rmin[rt] = (floatx4){3.0e38f, 3.0e38f, 3.0e38f, 3.0e38f};
    const floatx4 zero = {0.0f, 0.0f, 0.0f, 0.0f};

    const int ct0 = wave * 64;            // 64 col-tiles (of 16 pts) per wave
    const char* bbase = Bp + (size_t)(b * NPTS + ct0 * 16 + l15) * 32 + (quad & 1) * 16;

    // depth-4 register prefetch ring over 64 tiles, 512 B apart; wrap &63
    V16 t0, t1, t2, t3;
    t0.i = *(const int4*)(bbase);
    t1.i = *(const int4*)(bbase + 512);
    t2.i = *(const int4*)(bbase + 1024);
    t3.i = *(const int4*)(bbase + 1536);

    // unroll 1: one ring batch per iteration. The full 16-iter unroll +
    // the col-min consumer chain made the scheduler keep dozens of d
    // vectors live (R19/R20: 3KB/thread scratch, 600MB traffic, 245us).
#pragma unroll 1
    for (int i = 0; i < 64; i += 4) {
        V16 n0, n1, n2, n3;
        n0.i = *(const int4*)(bbase + (size_t)((i + 4) & 63) * 512);
        n1.i = *(const int4*)(bbase + (size_t)((i + 5) & 63) * 512);
        n2.i = *(const int4*)(bbase + (size_t)((i + 6) & 63) * 512);
        n3.i = *(const int4*)(bbase + (size_t)((i + 7) & 63) * 512);
#pragma unroll
        for (int u = 0; u < 4; u++) {
            const bf16x8 bf = (u == 0 ? t0.h : u == 1 ? t1.h : u == 2 ? t2.h : t3.h);
            float colacc = 3.0e38f;       // min over this quad's 4 rows x 4 rt
#pragma unroll
            for (int rt = 0; rt < 4; rt++) {
                const floatx4 d =
                    __builtin_amdgcn_mfma_f32_16x16x32_bf16(av[rt].h, bf, zero, 0, 0, 0);
#pragma unroll
                for (int r = 0; r < 4; r++)
                    rmin[rt][r] = fminf(rmin[rt][r], d[r]);
                colacc = fminf(colacc,
                               fminf(fminf(d[0], d[1]), fminf(d[2], d[3])));
            }
            // combine quads -> min over all 64 block rows; col = tile*16+l15
            colacc = fminf(colacc, __shfl_xor(colacc, 16, 64));
            colacc = fminf(colacc, __shfl_xor(colacc, 32, 64));
            if (quad == 0)
                sCol[wave][(i + u) * 16 + l15] = colacc;   // LDS, not global
        }
        t0 = n0; t1 = n1; t2 = n2; t3 = n3;
    }

    // ---- col side: one coalesced burst of this wave's 1024 partials ----
    {
        float4* cp4 = (float4*)((float*)(ws + OFF_CPART) +
                                (size_t)(b * 64 + stripe) * NPTS + ct0 * 16);
        const float4* s4 = (const float4*)sCol[wave];
#pragma unroll
        for (int k2 = 0; k2 < 4; k2++)
            cp4[k2 * 64 + lane] = s4[k2 * 64 + lane];
    }

    // ---- row side: butterfly min over the 16 col-lanes ----
#pragma unroll
    for (int off = 1; off < 16; off <<= 1) {
#pragma unroll
        for (int rt = 0; rt < 4; rt++)
#pragma unroll
            for (int r = 0; r < 4; r++)
                rmin[rt][r] = fminf(rmin[rt][r], __shfl_xor(rmin[rt][r], off, 64));
    }
    // quad leader holds rows rt*16 + quad*4 + r
    if (l15 == 0) {
#pragma unroll
        for (int rt = 0; rt < 4; rt++)
#pragma unroll
            for (int r = 0; r < 4; r++)
                sRow[wave][rt * 16 + quad * 4 + r] = rmin[rt][r];
    }
    __syncthreads();
    if (tid < 64) {
        float m = fminf(fminf(sRow[0][tid], sRow[1][tid]),
                        fminf(sRow[2][tid], sRow[3][tid]));
        m = fmaxf(m * 0.5f, 0.0f);        // undo K-replication doubling
        float g = m / (m + 1.0f);         // GM, MU=1
#pragma unroll
        for (int off = 1; off < 64; off <<= 1)
            g += __shfl_xor(g, off, 64);
        if (tid == 0)
            ((float*)(ws + OFF_BSUM))[blk] = g;   // plain store
    }
}

// ---- Kernel 3: stripe-min reduce of col partials + GM partial sums -------
__global__ __launch_bounds__(256)
void colreduce_kernel(char* __restrict__ ws) {
    const int blk = blockIdx.x;           // 0..127
    const int b   = blk & 7;              // match chamfer's XCD pinning
    const int cc  = blk >> 3;             // 0..15, 256-col chunk
    const int tid = threadIdx.x;
    const float* cp = (const float*)(ws + OFF_CPART) +
                      (size_t)b * 64 * NPTS + cc * 256 + tid;
    float m0 = 3.0e38f, m1 = 3.0e38f, m2 = 3.0e38f, m3 = 3.0e38f;
#pragma unroll 4
    for (int s = 0; s < 64; s += 4) {     // 4 chains for load ILP
        m0 = fminf(m0, cp[(size_t)(s + 0) * NPTS]);
        m1 = fminf(m1, cp[(size_t)(s + 1) * NPTS]);
        m2 = fminf(m2, cp[(size_t)(s + 2) * NPTS]);
        m3 = fminf(m3, cp[(size_t)(s + 3) * NPTS]);
    }
    float m = fminf(fminf(m0, m1), fminf(m2, m3));
    m = fmaxf(m * 0.5f, 0.0f);            // undo K-replication doubling
    float g = m / (m + 1.0f);             // GM, MU=1
#pragma unroll
    for (int off = 1; off < 64; off <<= 1)
        g += __shfl_xor(g, off, 64);
    __shared__ float sp[4];
    if ((tid & 63) == 0) sp[tid >> 6] = g;
    __syncthreads();
    if (tid == 0)
        ((float*)(ws + OFF_BSUM))[512 + blk] = sp[0] + sp[1] + sp[2] + sp[3];
}

// ---------------- Kernel 4: single-block finish ----------------
__global__ __launch_bounds__(256)
void final_kernel(const char* __restrict__ ws, float* __restrict__ out) {
    const float* bsum = (const float*)(ws + OFF_BSUM);
    const int tid = threadIdx.x;
    float g = bsum[tid] + bsum[tid + 256];          // row-side 512 partials
    if (tid < 128) g += bsum[512 + tid];            // col-side 128 partials
#pragma unroll
    for (int off = 1; off < 64; off <<= 1)
        g += __shfl_xor(g, off, 64);
    __shared__ float sp[4];
    if ((tid & 63) == 0) sp[tid >> 6] = g;
    __syncthreads();
    if (tid == 0)
        out[0] = (sp[0] + sp[1] + sp[2] + sp[3]) * (1.0f / (NB * NPTS));
}

extern "C" void kernel_launch(void* const* d_in, const int* in_sizes, int n_in,
                              void* d_out, int out_size, void* d_ws, size_t ws_size,
                              hipStream_t stream) {
    const float* srcs = (const float*)d_in[0];
    const float* tgts = (const float*)d_in[1];
    float* out = (float*)d_out;
    char* ws = (char*)d_ws;

    transform_kernel<<<dim3(128), dim3(256), 0, stream>>>(srcs, tgts, ws);
    chamfer_kernel<<<dim3(512), dim3(256), 0, stream>>>(ws);
    colreduce_kernel<<<dim3(128), dim3(256), 0, stream>>>(ws);
    final_kernel<<<dim3(1), dim3(256), 0, stream>>>(ws, out);
}

// Round 5
// 82.461 us; speedup vs baseline: 3.3064x; 1.0762x over previous
//
#include <hip/hip_runtime.h>

// GMLoss: bidirectional chamfer min + Geman-McClure penalty (MU=1).
// srcs, tgts: [B=8, D=3, N=4096] fp32. Output: scalar fp32.
//
// R23: single-pass bidirectional chamfer, SHUFFLE-FREE inner loop.
// Ladder of the single-pass arc:
//  - R19/R20: in-loop col-min with 2 shfl_xor per u-step + full 16-iter
//    unroll -> scheduler kept dozens of MFMA results live -> 3.1KB/thread
//    scratch spill (FETCH 203MB WRITE 412MB, 245us).
//  - R22: #pragma unroll 1 -> spill GONE (confirmed), total 88.7us, but
//    kernels ~45us: the in-loop chain MFMA -> fminf tree -> shfl(16) ->
//    shfl(32) -> LDS is latency-bound at 2 waves/SIMD; the two serialized
//    DS cross-lane ops x64 per wave dominate.
//  - R23: remove in-loop shuffles. Each lane stores its PER-QUAD 16-row
//    partial min to sColQ[wave][col*4+quad] (fire-and-forget ds_write, no
//    in-loop consumer; bank pattern l15*4+quad covers 32 banks exactly 2x
//    = conflict-free). Cross-quad min4 happens ONCE after the loop via
//    contiguous float4 LDS reads. In-loop consumer chain per d: 4 indep
//    rmin mins + tree -> store. VALU-throughput bound.
//
// Invariants (counter-evidenced, 23 rounds):
//  - #pragma unroll 1 on the i-loop; bound MFMA live ranges (R19/R20).
//  - NO cross-lane DS ops inside the MFMA loop (R22).
//  - NO device-scope fences or bulk atomics in hot kernels (R7/R9).
//  - __launch_bounds__(256,2) on chamfer; LDS 66.6KB still 2 blocks/CU.
//  - fp32 -> K=13 hi/lo bf16 packing, 16x16x32 MFMA with K-replication
//    (quads 2,3 re-read bytes 0..31 -> D=2P, halve after min).
//  - depth-4 register prefetch ring over B tiles.
// Single-pass: distance matrix ONCE per batch; row-min (per-src) in regs,
// col-min (per-tgt) per-quad partials -> LDS -> min4 -> cpart
// [b][stripe][4096] (8MB, written-once), stripe-min-reduced by colreduce.
// b = blk&7 pins each batch's Bpack + cpart round-trip to one XCD's L2.
// Accuracy: K=13 pack drops only lo.lo (~1e-5 << 1.26e-3); absmax 0.0 on
// R19/R20/R22.
//   A k: [-2sh(3), -2sl(3), -2sh(3), s2h, s2l, 1, 1, 0,0,0]
//   B k: [ th(3),   th(3),   tl(3),  1, 1, t2h, t2l, 0,0,0]
// 16x16x32 layouts (m89/m91): A[m=lane&15][k=(lane>>4)*8+j], B same
// (n=lane&15); D: col=lane&15, row=(lane>>4)*4+reg (so quad q holds rows
// q*4..q*4+3 of each 16-row tile -> per-quad partial covers 16 of 64 rows).
// Budget: ~40-43us harness d_ws re-poison (268MB fill, timed) + kernels.

#define NPTS 4096
#define NB   8

typedef __attribute__((ext_vector_type(8))) short bf16x8;
typedef __attribute__((ext_vector_type(4))) float floatx4;

// ws layout: Apack[srcs] (1MB), Bpack[tgts] (1MB), colpart (8MB), bsum[640]
#define OFF_APACK 0u
#define OFF_BPACK (1u << 20)
#define OFF_CPART (2u << 20)
#define OFF_BSUM  (10u << 20)

union V16 { int4 i; bf16x8 h; };

__device__ __forceinline__ unsigned short f2bf(float f) {
    unsigned u = __float_as_uint(f);
    u += 0x7FFFu + ((u >> 16) & 1u);       // RNE
    return (unsigned short)(u >> 16);
}
__device__ __forceinline__ float bf2f(unsigned short h) {
    return __uint_as_float(((unsigned)h) << 16);
}
__device__ __forceinline__ int pk(unsigned short lo, unsigned short hi) {
    return (int)((unsigned)lo | ((unsigned)hi << 16));
}

// ---------------- Kernel 1: pack A-style(srcs) + B-style(tgts) -------------
__device__ __forceinline__ void pack_A(const float* __restrict__ cloud,
                                       int b, int j, int gid,
                                       char* __restrict__ apack) {
    const unsigned short ONE = 0x3F80;
    const float* p = cloud + b * 3 * NPTS;
    const float x = p[j], y = p[NPTS + j], z = p[2 * NPTS + j];
    const unsigned short hx = f2bf(x), hy = f2bf(y), hz = f2bf(z);
    const unsigned short a0 = f2bf(-2.0f * bf2f(hx));
    const unsigned short a1 = f2bf(-2.0f * bf2f(hy));
    const unsigned short a2 = f2bf(-2.0f * bf2f(hz));
    const unsigned short m0 = f2bf(-2.0f * (x - bf2f(hx)));
    const unsigned short m1 = f2bf(-2.0f * (y - bf2f(hy)));
    const unsigned short m2 = f2bf(-2.0f * (z - bf2f(hz)));
    const float n2 = fmaf(z, z, fmaf(y, y, x * x));
    const unsigned short n2h = f2bf(n2);
    const unsigned short n2l = f2bf(n2 - bf2f(n2h));
    int4* Ap = (int4*)(apack + (size_t)gid * 32);
    Ap[0] = make_int4(pk(a0, a1), pk(a2, m0), pk(m1, m2), pk(a0, a1));
    Ap[1] = make_int4(pk(a2, n2h), pk(n2l, ONE), pk(ONE, 0), 0);
}

__device__ __forceinline__ void pack_B(const float* __restrict__ cloud,
                                       int b, int j, int gid,
                                       char* __restrict__ bpack) {
    const unsigned short ONE = 0x3F80;
    const float* p = cloud + b * 3 * NPTS;
    const float x = p[j], y = p[NPTS + j], z = p[2 * NPTS + j];
    const unsigned short hx = f2bf(x), hy = f2bf(y), hz = f2bf(z);
    const unsigned short lx = f2bf(x - bf2f(hx));
    const unsigned short ly = f2bf(y - bf2f(hy));
    const unsigned short lz = f2bf(z - bf2f(hz));
    const float n2 = fmaf(z, z, fmaf(y, y, x * x));
    const unsigned short n2h = f2bf(n2);
    const unsigned short n2l = f2bf(n2 - bf2f(n2h));
    int4* Bp = (int4*)(bpack + (size_t)gid * 32);
    Bp[0] = make_int4(pk(hx, hy), pk(hz, hx), pk(hy, hz), pk(lx, ly));
    Bp[1] = make_int4(pk(lz, ONE), pk(ONE, n2h), pk(n2l, 0), 0);
}

__global__ __launch_bounds__(256)
void transform_kernel(const float* __restrict__ srcs,
                      const float* __restrict__ tgts,
                      char* __restrict__ ws) {
    const int gid = blockIdx.x * 256 + threadIdx.x;   // 0..32767 = b*4096+j
    const int b = gid >> 12, j = gid & 4095;
    pack_A(srcs, b, j, gid, ws + OFF_APACK);
    pack_B(tgts, b, j, gid, ws + OFF_BPACK);
}

// ------- Kernel 2: single-pass bidirectional MFMA chamfer (64 rows) -------
__global__ __launch_bounds__(256, 2)
void chamfer_kernel(char* __restrict__ ws) {
    const int blk    = blockIdx.x;        // 0..511
    const int b      = blk & 7;           // XCD-pinned batch
    const int stripe = blk >> 3;          // 0..63, 64 src rows each
    const int tid    = threadIdx.x;
    const int wave   = tid >> 6;          // 0..3
    const int lane   = tid & 63;
    const int l15    = lane & 15;
    const int quad   = lane >> 4;         // k-half = (quad&1)*16 bytes

    const char* Ap = ws + OFF_APACK;
    const char* Bp = ws + OFF_BPACK;

    // per-wave per-quad col partials: [wave][col*4+quad], 16KB/wave
    __shared__ __align__(16) float sColQ[4][4096];
    __shared__ float sRow[4][64];

    // 4 row-tiles of 16 rows; quads 2,3 replicate quads 0,1 -> D = 2P.
    V16 av[4];
#pragma unroll
    for (int rt = 0; rt < 4; rt++)
        av[rt].i = *(const int4*)(Ap +
            (size_t)(b * NPTS + stripe * 64 + rt * 16 + l15) * 32 + (quad & 1) * 16);

    floatx4 rmin[4];
#pragma unroll
    for (int rt = 0; rt < 4; rt++)
        rmin[rt] = (floatx4){3.0e38f, 3.0e38f, 3.0e38f, 3.0e38f};
    const floatx4 zero = {0.0f, 0.0f, 0.0f, 0.0f};

    const int ct0 = wave * 64;            // 64 col-tiles (of 16 pts) per wave
    const char* bbase = Bp + (size_t)(b * NPTS + ct0 * 16 + l15) * 32 + (quad & 1) * 16;
    float* sq = sColQ[wave];

    // depth-4 register prefetch ring over 64 tiles, 512 B apart; wrap &63
    V16 t0, t1, t2, t3;
    t0.i = *(const int4*)(bbase);
    t1.i = *(const int4*)(bbase + 512);
    t2.i = *(const int4*)(bbase + 1024);
    t3.i = *(const int4*)(bbase + 1536);

    // unroll 1: one ring batch per trip; bounded MFMA live ranges (R19/R20
    // spilled 3KB/thread with the flattened 256-MFMA body).
#pragma unroll 1
    for (int i = 0; i < 64; i += 4) {
        V16 n0, n1, n2, n3;
        n0.i = *(const int4*)(bbase + (size_t)((i + 4) & 63) * 512);
        n1.i = *(const int4*)(bbase + (size_t)((i + 5) & 63) * 512);
        n2.i = *(const int4*)(bbase + (size_t)((i + 6) & 63) * 512);
        n3.i = *(const int4*)(bbase + (size_t)((i + 7) & 63) * 512);
#pragma unroll
        for (int u = 0; u < 4; u++) {
            const bf16x8 bf = (u == 0 ? t0.h : u == 1 ? t1.h : u == 2 ? t2.h : t3.h);
            float colq = 3.0e38f;         // min over this quad's 16 rows
#pragma unroll
            for (int rt = 0; rt < 4; rt++) {
                const floatx4 d =
                    __builtin_amdgcn_mfma_f32_16x16x32_bf16(av[rt].h, bf, zero, 0, 0, 0);
#pragma unroll
                for (int r = 0; r < 4; r++)
                    rmin[rt][r] = fminf(rmin[rt][r], d[r]);
                colq = fminf(colq,
                             fminf(fminf(d[0], d[1]), fminf(d[2], d[3])));
            }
            // fire-and-forget per-quad partial; NO cross-lane ops in loop.
            // bank = (l15*4+quad)%32: 32 banks hit exactly 2x = conflict-free
            sq[((i + u) * 16 + l15) * 4 + quad] = colq;
        }
        t0 = n0; t1 = n1; t2 = n2; t3 = n3;
    }

    // ---- row side: butterfly min over the 16 col-lanes ----
#pragma unroll
    for (int off = 1; off < 16; off <<= 1) {
#pragma unroll
        for (int rt = 0; rt < 4; rt++)
#pragma unroll
            for (int r = 0; r < 4; r++)
                rmin[rt][r] = fminf(rmin[rt][r], __shfl_xor(rmin[rt][r], off, 64));
    }
    // quad leader holds rows rt*16 + quad*4 + r
    if (l15 == 0) {
#pragma unroll
        for (int rt = 0; rt < 4; rt++)
#pragma unroll
            for (int r = 0; r < 4; r++)
                sRow[wave][rt * 16 + quad * 4 + r] = rmin[rt][r];
    }
    __syncthreads();

    // ---- col side: cross-quad min4 + coalesced store to cpart ----
    {
        float* cp = (float*)(ws + OFF_CPART) +
                    (size_t)(b * 64 + stripe) * NPTS + ct0 * 16;
#pragma unroll
        for (int k2 = 0; k2 < 16; k2++) {
            const int c = k2 * 64 + lane;
            const float4 v = *(const float4*)&sq[c * 4];
            cp[c] = fminf(fminf(v.x, v.y), fminf(v.z, v.w));
        }
    }

    if (tid < 64) {
        float m = fminf(fminf(sRow[0][tid], sRow[1][tid]),
                        fminf(sRow[2][tid], sRow[3][tid]));
        m = fmaxf(m * 0.5f, 0.0f);        // undo K-replication doubling
        float g = m / (m + 1.0f);         // GM, MU=1
#pragma unroll
        for (int off = 1; off < 64; off <<= 1)
            g += __shfl_xor(g, off, 64);
        if (tid == 0)
            ((float*)(ws + OFF_BSUM))[blk] = g;   // plain store
    }
}

// ---- Kernel 3: stripe-min reduce of col partials + GM partial sums -------
__global__ __launch_bounds__(256)
void colreduce_kernel(char* __restrict__ ws) {
    const int blk = blockIdx.x;           // 0..127
    const int b   = blk & 7;              // match chamfer's XCD pinning
    const int cc  = blk >> 3;             // 0..15, 256-col chunk
    const int tid = threadIdx.x;
    const float* cp = (const float*)(ws + OFF_CPART) +
                      (size_t)b * 64 * NPTS + cc * 256 + tid;
    float m0 = 3.0e38f, m1 = 3.0e38f, m2 = 3.0e38f, m3 = 3.0e38f;
#pragma unroll 4
    for (int s = 0; s < 64; s += 4) {     // 4 chains for load ILP
        m0 = fminf(m0, cp[(size_t)(s + 0) * NPTS]);
        m1 = fminf(m1, cp[(size_t)(s + 1) * NPTS]);
        m2 = fminf(m2, cp[(size_t)(s + 2) * NPTS]);
        m3 = fminf(m3, cp[(size_t)(s + 3) * NPTS]);
    }
    float m = fminf(fminf(m0, m1), fminf(m2, m3));
    m = fmaxf(m * 0.5f, 0.0f);            // undo K-replication doubling
    float g = m / (m + 1.0f);             // GM, MU=1
#pragma unroll
    for (int off = 1; off < 64; off <<= 1)
        g += __shfl_xor(g, off, 64);
    __shared__ float sp[4];
    if ((tid & 63) == 0) sp[tid >> 6] = g;
    __syncthreads();
    if (tid == 0)
        ((float*)(ws + OFF_BSUM))[512 + blk] = sp[0] + sp[1] + sp[2] + sp[3];
}

// ---------------- Kernel 4: single-block finish ----------------
__global__ __launch_bounds__(256)
void final_kernel(const char* __restrict__ ws, float* __restrict__ out) {
    const float* bsum = (const float*)(ws + OFF_BSUM);
    const int tid = threadIdx.x;
    float g = bsum[tid] + bsum[tid + 256];          // row-side 512 partials
    if (tid < 128) g += bsum[512 + tid];            // col-side 128 partials
#pragma unroll
    for (int off = 1; off < 64; off <<= 1)
        g += __shfl_xor(g, off, 64);
    __shared__ float sp[4];
    if ((tid & 63) == 0) sp[tid >> 6] = g;
    __syncthreads();
    if (tid == 0)
        out[0] = (sp[0] + sp[1] + sp[2] + sp[3]) * (1.0f / (NB * NPTS));
}

extern "C" void kernel_launch(void* const* d_in, const int* in_sizes, int n_in,
                              void* d_out, int out_size, void* d_ws, size_t ws_size,
                              hipStream_t stream) {
    const float* srcs = (const float*)d_in[0];
    const float* tgts = (const float*)d_in[1];
    float* out = (float*)d_out;
    char* ws = (char*)d_ws;

    transform_kernel<<<dim3(128), dim3(256), 0, stream>>>(srcs, tgts, ws);
    chamfer_kernel<<<dim3(512), dim3(256), 0, stream>>>(ws);
    colreduce_kernel<<<dim3(128), dim3(256), 0, stream>>>(ws);
    final_kernel<<<dim3(1), dim3(256), 0, stream>>>(ws, out);
}